// Round 1
// baseline (4972.462 us; speedup 1.0000x reference)
//
#include <hip/hip_runtime.h>
#include <hip/hip_cooperative_groups.h>

// Persistent cooperative LSTM kernel.
// R1..R5 history: grid.sync -> hand barrier -> coherent IC path -> decoupled group
//   chains w/ flag words + wave-parallel polling: 5.7us/step.
// R6: ELIMINATE the flag protocol. Every h pair is stored as one atomic
//   u64 {2xbf16 | step-tag}. Consumers poll tags ON the data words themselves:
//   - no vmcnt(0) drain before publishing (store carries its own tag)
//   - no separate flag store / flag poll RTT (poll IS the data load)
//   - no per-step __syncthreads (the 2 waves of a WG are independent pipelines)
//   Ring safety: L0 overwrite of h0 slot t&3 gated by L1 output tags >= t-3
//   (merged into the same poll round); all other reuse hazards follow
//   transitively from observed output tags (outputs depend on all inputs).
//   x-part GEMM hoisted before the poll (h-independent).
//   tgt buffer moved into out[256..] (saves 128KB of workspace).

typedef short v8s __attribute__((ext_vector_type(8)));
typedef float v4f __attribute__((ext_vector_type(4)));
typedef unsigned long long u64;

#define S_LEN 512
#define BATCH 64
#define EMBD  300
#define XPAD  320
#define ROWP0 584   // 320 (x, padded) + 256 (h) + 8 pad
#define ROWP1 776   // 512 (x1) + 256 (h) + 8 pad
#define NWG   256

// workspace layout (bytes):
//   Xbuf[512][64][320] bf16              @ 0          (20,971,520)
//   h0t  u64[4][64][256] {pair|tag}      @ 20,971,520 (524,288)
//   h1t  u64[2][64][256] {pair|tag}      @ 21,495,808 (262,144)
//   eflag u32[256] (pad 1KB)             @ 21,757,952 (1,024)   top: 21,758,976
#define H0T_OFF   20971520u
#define H1T_OFF   (H0T_OFF + 524288u)
#define EFLAG_OFF (H1T_OFF + 262144u)
#define ZERO_U64  98432   // (524288 + 262144 + 1024) / 8

__device__ inline unsigned short f2bf(float x) {
  union { float f; unsigned u; } v; v.f = x;
  unsigned r = v.u + 0x7FFF + ((v.u >> 16) & 1);   // RNE
  return (unsigned short)(r >> 16);
}
__device__ inline float sigm(float x) { return 1.f / (1.f + __expf(-x)); }
__device__ inline float tanhf_(float x) {
  float e = __expf(-2.f * fabsf(x));
  float r = (1.f - e) / (1.f + e);
  return x >= 0.f ? r : -r;
}

// IC-coherent (sc0 sc1) accessors — SYSTEM scope, proven data path.
__device__ inline u64 ld_sys64(const u64* p) {
  return __hip_atomic_load(p, __ATOMIC_RELAXED, __HIP_MEMORY_SCOPE_SYSTEM);
}
__device__ inline void st8_sys(u64* p, u64 v) {
  __hip_atomic_store(p, v, __ATOMIC_RELAXED, __HIP_MEMORY_SCOPE_SYSTEM);
}
__device__ inline unsigned ldu_sys(const unsigned* p) {
  return __hip_atomic_load(p, __ATOMIC_RELAXED, __HIP_MEMORY_SCOPE_SYSTEM);
}
__device__ inline void st4_sys(unsigned* p, unsigned v) {
  __hip_atomic_store(p, v, __ATOMIC_RELAXED, __HIP_MEMORY_SCOPE_SYSTEM);
}
__device__ inline void stf_sys(float* p, float v) {
  __hip_atomic_store(p, v, __ATOMIC_RELAXED, __HIP_MEMORY_SCOPE_SYSTEM);
}
__device__ inline float ldf_sys(const float* p) {
  return __hip_atomic_load(p, __ATOMIC_RELAXED, __HIP_MEMORY_SCOPE_SYSTEM);
}

__global__ void __launch_bounds__(128, 1)
ContextAwareModel_9655086481739_kernel(
    const int* __restrict__ contexts, const int* __restrict__ positions,
    const float* __restrict__ emb,
    const float* __restrict__ wih0, const float* __restrict__ whh0,
    const float* __restrict__ bih0, const float* __restrict__ bhh0,
    const float* __restrict__ wih1, const float* __restrict__ whh1,
    const float* __restrict__ bih1, const float* __restrict__ bhh1,
    const float* __restrict__ wcls, const float* __restrict__ bcls,
    float* __restrict__ out, unsigned char* __restrict__ ws)
{
  __shared__ unsigned short smem[32 * ROWP1];   // 49,664 B

  const int wg   = blockIdx.x;
  const int tid  = threadIdx.x;
  const int layer  = wg >> 7;
  const int d      = (wg >> 6) & 1;
  const int colblk = (wg >> 1) & 31;
  const int mhalf  = wg & 1;
  const int wv   = tid >> 6;
  const int lane = tid & 63;
  const int quad = lane >> 4;
  const int lc   = lane & 15;
  const int hc0  = colblk * 8;
  const int hc   = hc0 + (lc & 7);
  const int m0   = mhalf * 32 + wv * 16;
  const int r_base = m0 + quad * 4;

  unsigned short* Xbuf = (unsigned short*)ws;
  u64*      h0t   = (u64*)(ws + H0T_OFF);
  u64*      h1t   = (u64*)(ws + H1T_OFF);
  unsigned* eflag = (unsigned*)(ws + EFLAG_OFF);
  float*    tgt   = out + 256;                 // target_output lives in out directly

  const int ROWP = layer ? ROWP1 : ROWP0;

  // ---------------- stage 0 ----------------
  { // zero all tag-carrying words + end flags (fresh every launch)
    u64* zp = (u64*)(ws + H0T_OFF);
    for (int i = wg * 128 + tid; i < ZERO_U64; i += NWG * 128)
      st8_sys(zp + i, 0ull);
  }
  { // embedding gather -> bf16, padded to 320
    int gw2 = wg * 2 + wv;                     // 0..511 waves
    for (int rl = 0; rl < 64; ++rl) {
      int rr = gw2 * 64 + rl;                  // rr = t*64 + b
      int t = rr >> 6, b = rr & 63;
      int tok = contexts[b * S_LEN + t];
      const float* erow = emb + (long)tok * EMBD;
#pragma unroll
      for (int i = 0; i < 5; ++i) {
        int kk = i * 64 + lane;
        float v = (kk < EMBD) ? erow[kk] : 0.f;
        if (kk < XPAD) Xbuf[rr * XPAD + kk] = f2bf(v);
      }
    }
  }
  { // weights -> LDS (bf16). Row lr: tile T=lr>>4, col c=lr&15, gate = T*2+(c>>3)
    const float* wih = layer ? wih1 : wih0;
    const float* whh = layer ? whh1 : whh0;
    const int KI  = layer ? 512 : 300;
    const int KIp = layer ? 512 : 320;
    const int KT  = layer ? 768 : 576;
    int lr = tid >> 2, sub = tid & 3;
    int c = lr & 15, T = lr >> 4;
    int gate = T * 2 + (c >> 3);
    int j = gate * 256 + hc0 + (c & 7);
    const float* wri = wih + (long)(d * 1024 + j) * KI;
    const float* wrh = whh + (long)(d * 1024 + j) * 256;
    for (int kk = sub; kk < ROWP; kk += 4) {
      float v = 0.f;
      if (kk < KI) v = wri[kk];
      else if (kk >= KIp && kk < KT) v = wrh[kk - KIp];
      smem[lr * ROWP + kk] = f2bf(v);
    }
  }
  float bias0, bias1;
  {
    const float* bi = layer ? bih1 : bih0;
    const float* bh = layer ? bhh1 : bhh0;
    int j0 = ((lc >> 3) & 1) * 256 + hc;        // gate i/f
    int j1 = (2 + ((lc >> 3) & 1)) * 256 + hc;  // gate g/o
    bias0 = bi[d * 1024 + j0] + bh[d * 1024 + j0];
    bias1 = bi[d * 1024 + j1] + bh[d * 1024 + j1];
  }
  int pos[4];
#pragma unroll
  for (int j = 0; j < 4; ++j) pos[j] = positions[r_base + j];
  float cst[4] = {0.f, 0.f, 0.f, 0.f};
  const unsigned short* lds_t0 = smem + lc * ROWP + quad * 8;
  const unsigned short* lds_t1 = smem + (16 + lc) * ROWP + quad * 8;
  const bool hi = (lc & 8) != 0;

  // one cooperative sync: publishes Xbuf, LDS weights, zeroed tags
  cooperative_groups::grid_group gg = cooperative_groups::this_grid();
  __syncthreads();
  gg.sync();

  // ---------------- recurrence: tag-paced wave pipelines ----------------
  if (layer == 0) {
    for (int t = 0; t < S_LEN; ++t) {
      v4f acc0 = {bias0, bias0, bias0, bias0};
      v4f acc1 = {bias1, bias1, bias1, bias1};
      { // x-part GEMM: h-independent, runs before the poll
        const unsigned short* aP1 = Xbuf + (t * BATCH + m0 + lc) * XPAD + quad * 8;
#pragma unroll
        for (int i = 0; i < 10; ++i) {
          v8s av = *(const v8s*)(aP1 + i * 32);
          v8s b0 = *(const v8s*)(lds_t0 + i * 32);
          v8s b1 = *(const v8s*)(lds_t1 + i * 32);
          acc0 = __builtin_amdgcn_mfma_f32_16x16x32_bf16(av, b0, acc0, 0, 0, 0);
          acc1 = __builtin_amdgcn_mfma_f32_16x16x32_bf16(av, b1, acc1, 0, 0, 0);
        }
      }
      if (t > 0) { // h0_{t-1}, own dir, tag == t; merged back-pressure tag >= t-3
        const u64* hp = h0t + (((t + 3) & 3) * 16384 + (m0 + lc) * 256 + d * 128 + quad * 4);
        const unsigned T = (unsigned)t;
        const bool dobp = (t >= 4);
        const u64* bp = h1t + ((t & 1) * 16384 + m0 * 256 + (lane >> 5) * 128 + (lane & 31) * 4);
        const unsigned bthr = (unsigned)(t - 3);
        u64 w[32];
        for (;;) {
#pragma unroll
          for (int i = 0; i < 8; ++i)
#pragma unroll
            for (int k = 0; k < 4; ++k)
              w[i * 4 + k] = ld_sys64(hp + i * 16 + k);
          unsigned diff = 0;
#pragma unroll
          for (int i = 0; i < 32; ++i) diff |= (unsigned)(w[i] >> 32) ^ T;
          bool ok = (diff == 0);
          if (dobp) ok = ok && ((unsigned)(ld_sys64(bp) >> 32) >= bthr);
          if (__all(ok)) break;
          __builtin_amdgcn_s_sleep(1);
        }
#pragma unroll
        for (int i = 0; i < 8; ++i) {
          union { unsigned u[4]; v8s s; } f;
          f.u[0] = (unsigned)w[i * 4 + 0];
          f.u[1] = (unsigned)w[i * 4 + 1];
          f.u[2] = (unsigned)w[i * 4 + 2];
          f.u[3] = (unsigned)w[i * 4 + 3];
          v8s b0 = *(const v8s*)(lds_t0 + 320 + i * 32);
          v8s b1 = *(const v8s*)(lds_t1 + 320 + i * 32);
          acc0 = __builtin_amdgcn_mfma_f32_16x16x32_bf16(f.s, b0, acc0, 0, 0, 0);
          acc1 = __builtin_amdgcn_mfma_f32_16x16x32_bf16(f.s, b1, acc1, 0, 0, 0);
        }
      }
      const u64 tagbits = ((u64)(unsigned)(t + 1)) << 32;
#pragma unroll
      for (int j = 0; j < 4; ++j) {
        float a0 = acc0[j], a1 = acc1[j];
        float o0 = __shfl_xor(a0, 8);
        float o1 = __shfl_xor(a1, 8);
        float iv = hi ? o0 : a0;
        float fv = hi ? a0 : o0;
        float gv = hi ? o1 : a1;
        float ov = hi ? a1 : o1;
        float ii = sigm(iv), ff = sigm(fv), ggt = tanhf_(gv), oo = sigm(ov);
        float cn = ff * cst[j] + ii * ggt;
        cst[j] = cn;
        float hv = oo * tanhf_(cn);
        unsigned hb = f2bf(hv);
        unsigned ob = ((unsigned)__shfl_xor((int)hb, 1)) & 0xFFFFu;
        if (lc < 8 && !(lc & 1)) {
          unsigned word = hb | (ob << 16);
          st8_sys(h0t + ((t & 3) * 16384 + (r_base + j) * 256 + d * 128 + colblk * 4 + (lc >> 1)),
                  (u64)word | tagbits);
        }
      }
    }
  } else {
    for (int t = 0; t < S_LEN; ++t) {
      v4f acc0 = {bias0, bias0, bias0, bias0};
      v4f acc1 = {bias1, bias1, bias1, bias1};
      if (t > 0) { // phase A: h1_{t-1}, own dir ring, tag == t
        const u64* hp = h1t + ((((t + 1) & 1)) * 16384 + (m0 + lc) * 256 + d * 128 + quad * 4);
        const unsigned T = (unsigned)t;
        u64 w[32];
        for (;;) {
#pragma unroll
          for (int i = 0; i < 8; ++i)
#pragma unroll
            for (int k = 0; k < 4; ++k)
              w[i * 4 + k] = ld_sys64(hp + i * 16 + k);
          unsigned diff = 0;
#pragma unroll
          for (int i = 0; i < 32; ++i) diff |= (unsigned)(w[i] >> 32) ^ T;
          if (__all(diff == 0)) break;
          __builtin_amdgcn_s_sleep(1);
        }
#pragma unroll
        for (int i = 0; i < 8; ++i) {
          union { unsigned u[4]; v8s s; } f;
          f.u[0] = (unsigned)w[i * 4 + 0];
          f.u[1] = (unsigned)w[i * 4 + 1];
          f.u[2] = (unsigned)w[i * 4 + 2];
          f.u[3] = (unsigned)w[i * 4 + 3];
          v8s b0 = *(const v8s*)(lds_t0 + 512 + i * 32);
          v8s b1 = *(const v8s*)(lds_t1 + 512 + i * 32);
          acc0 = __builtin_amdgcn_mfma_f32_16x16x32_bf16(f.s, b0, acc0, 0, 0, 0);
          acc1 = __builtin_amdgcn_mfma_f32_16x16x32_bf16(f.s, b1, acc1, 0, 0, 0);
        }
      }
      { // phase B: h0_t, both dirs, tag == t+1 (produced this step by layer0)
        const u64* hp = h0t + ((t & 3) * 16384 + (m0 + lc) * 256 + quad * 4);
        const unsigned T = (unsigned)(t + 1);
        u64 w[64];
        for (;;) {
#pragma unroll
          for (int i = 0; i < 16; ++i)
#pragma unroll
            for (int k = 0; k < 4; ++k)
              w[i * 4 + k] = ld_sys64(hp + i * 16 + k);
          unsigned diff = 0;
#pragma unroll
          for (int i = 0; i < 64; ++i) diff |= (unsigned)(w[i] >> 32) ^ T;
          if (__all(diff == 0)) break;
          __builtin_amdgcn_s_sleep(1);
        }
#pragma unroll
        for (int i = 0; i < 16; ++i) {
          union { unsigned u[4]; v8s s; } f;
          f.u[0] = (unsigned)w[i * 4 + 0];
          f.u[1] = (unsigned)w[i * 4 + 1];
          f.u[2] = (unsigned)w[i * 4 + 2];
          f.u[3] = (unsigned)w[i * 4 + 3];
          v8s b0 = *(const v8s*)(lds_t0 + i * 32);
          v8s b1 = *(const v8s*)(lds_t1 + i * 32);
          acc0 = __builtin_amdgcn_mfma_f32_16x16x32_bf16(f.s, b0, acc0, 0, 0, 0);
          acc1 = __builtin_amdgcn_mfma_f32_16x16x32_bf16(f.s, b1, acc1, 0, 0, 0);
        }
      }
      const u64 tagbits = ((u64)(unsigned)(t + 1)) << 32;
#pragma unroll
      for (int j = 0; j < 4; ++j) {
        float a0 = acc0[j], a1 = acc1[j];
        float o0 = __shfl_xor(a0, 8);
        float o1 = __shfl_xor(a1, 8);
        float iv = hi ? o0 : a0;
        float fv = hi ? a0 : o0;
        float gv = hi ? o1 : a1;
        float ov = hi ? a1 : o1;
        float ii = sigm(iv), ff = sigm(fv), ggt = tanhf_(gv), oo = sigm(ov);
        float cn = ff * cst[j] + ii * ggt;
        cst[j] = cn;
        float hv = oo * tanhf_(cn);
        unsigned hb = f2bf(hv);
        unsigned ob = ((unsigned)__shfl_xor((int)hb, 1)) & 0xFFFFu;
        int r = r_base + j;
        if (lc < 8 && !(lc & 1)) {
          unsigned word = hb | (ob << 16);
          st8_sys(h1t + ((t & 1) * 16384 + r * 256 + d * 128 + colblk * 4 + (lc >> 1)),
                  (u64)word | tagbits);
        }
        if (lc < 8 && pos[j] == t) stf_sys(&tgt[r * 512 + d * 256 + hc], hv);
      }
    }
    // publish completion: tgt stores drained, then end flag (release pattern)
    asm volatile("s_waitcnt vmcnt(0)" ::: "memory");
    st4_sys(eflag + (wg - 128) * 2 + wv, 1u);
  }

  // ---------------- epilogue (layer-0 wg<64 waves only) ----------------
  {
    int gw = wg * 2 + wv;
    if (gw < 128) {                 // one wave per (b, class)
      for (;;) {                    // join: all 256 layer-1 waves finished
        bool ok = true;
#pragma unroll
        for (int k = 0; k < 4; ++k) ok &= (ldu_sys(eflag + k * 64 + lane) != 0u);
        if (__all(ok)) break;
        __builtin_amdgcn_s_sleep(4);
      }
      int b = gw >> 1, cl2 = gw & 1;
      float s = 0.f;
#pragma unroll
      for (int i = 0; i < 8; ++i) {
        int jj = i * 64 + lane;
        s += ldf_sys(&tgt[b * 512 + jj]) * wcls[cl2 * 512 + jj];
      }
      s += __shfl_xor(s, 32); s += __shfl_xor(s, 16); s += __shfl_xor(s, 8);
      s += __shfl_xor(s, 4);  s += __shfl_xor(s, 2);  s += __shfl_xor(s, 1);
      if (lane == 0) {
        float L = s + bcls[cl2];
        out[b * 2 + cl2] = L;             // logits
        out[128 + b * 2 + cl2] = sigm(L); // probs
      }
    }
  }
}

extern "C" void kernel_launch(void* const* d_in, const int* in_sizes, int n_in,
                              void* d_out, int out_size, void* d_ws, size_t ws_size,
                              hipStream_t stream) {
  (void)in_sizes; (void)n_in; (void)out_size; (void)ws_size;
  const int*   contexts  = (const int*)d_in[0];
  const int*   positions = (const int*)d_in[1];
  const float* emb   = (const float*)d_in[2];
  const float* wih0  = (const float*)d_in[3];
  const float* whh0  = (const float*)d_in[4];
  const float* bih0  = (const float*)d_in[5];
  const float* bhh0  = (const float*)d_in[6];
  const float* wih1  = (const float*)d_in[7];
  const float* whh1  = (const float*)d_in[8];
  const float* bih1  = (const float*)d_in[9];
  const float* bhh1  = (const float*)d_in[10];
  const float* wcls  = (const float*)d_in[11];
  const float* bcls  = (const float*)d_in[12];
  float* out = (float*)d_out;
  unsigned char* ws = (unsigned char*)d_ws;

  void* args[] = { &contexts, &positions, &emb,
                   &wih0, &whh0, &bih0, &bhh0,
                   &wih1, &whh1, &bih1, &bhh1,
                   &wcls, &bcls, &out, &ws };
  hipLaunchCooperativeKernel((const void*)ContextAwareModel_9655086481739_kernel,
                             dim3(NWG), dim3(128), args, 0, stream);
}

// Round 2
// 4498.948 us; speedup vs baseline: 1.1052x; 1.1052x over previous
//
#include <hip/hip_runtime.h>
#include <hip/hip_cooperative_groups.h>

// Persistent cooperative LSTM kernel.
// R1..R5: grid.sync -> hand barrier -> coherent IC path -> decoupled group chains
//   w/ flag words + wave-parallel polling: 5.7us/step.
// R6 (REGRESSED 9.5us/step): tags on every data u64, but the poll loop re-loaded
//   the full 16-32KB operand block every spin round -> FETCH +173MB, RTT+transfer
//   serialized per round.
// R7: keep tagged u64 data words {2xbf16 | step-tag} (no producer drain, no flag
//   store, correctness by tag-verify on the words fed to MFMA), but SPLIT wait
//   from load:
//   - spin touches only 1-2 SENTINEL words/lane (producer's last-stored word,
//     row m0+15 word 3) -> 64 lanes cover all producers in one small RTT/round
//   - bulk operand load runs ONCE after sentinels pass, tag-verified, with a
//     (rare) retry loop as correct fallback for straggler visibility
//   - sentinel loads issue before the x-part MFMAs (overlap first RTT)
//   - back-pressure words merged into the same spin round (lanes 32-63)

typedef short v8s __attribute__((ext_vector_type(8)));
typedef float v4f __attribute__((ext_vector_type(4)));
typedef unsigned long long u64;

#define S_LEN 512
#define BATCH 64
#define EMBD  300
#define XPAD  320
#define ROWP0 584   // 320 (x, padded) + 256 (h) + 8 pad
#define ROWP1 776   // 512 (x1) + 256 (h) + 8 pad
#define NWG   256

// workspace layout (bytes):
//   Xbuf[512][64][320] bf16              @ 0          (20,971,520)
//   h0t  u64[4][64][256] {pair|tag}      @ 20,971,520 (524,288)
//   h1t  u64[2][64][256] {pair|tag}      @ 21,495,808 (262,144)
//   eflag u32[256] (pad 1KB)             @ 21,757,952 (1,024)   top: 21,758,976
#define H0T_OFF   20971520u
#define H1T_OFF   (H0T_OFF + 524288u)
#define EFLAG_OFF (H1T_OFF + 262144u)
#define ZERO_U64  98432   // (524288 + 262144 + 1024) / 8

__device__ inline unsigned short f2bf(float x) {
  union { float f; unsigned u; } v; v.f = x;
  unsigned r = v.u + 0x7FFF + ((v.u >> 16) & 1);   // RNE
  return (unsigned short)(r >> 16);
}
__device__ inline float sigm(float x) { return 1.f / (1.f + __expf(-x)); }
__device__ inline float tanhf_(float x) {
  float e = __expf(-2.f * fabsf(x));
  float r = (1.f - e) / (1.f + e);
  return x >= 0.f ? r : -r;
}

// IC-coherent (sc0 sc1) accessors — SYSTEM scope, proven data path.
__device__ inline u64 ld_sys64(const u64* p) {
  return __hip_atomic_load(p, __ATOMIC_RELAXED, __HIP_MEMORY_SCOPE_SYSTEM);
}
__device__ inline void st8_sys(u64* p, u64 v) {
  __hip_atomic_store(p, v, __ATOMIC_RELAXED, __HIP_MEMORY_SCOPE_SYSTEM);
}
__device__ inline unsigned ldu_sys(const unsigned* p) {
  return __hip_atomic_load(p, __ATOMIC_RELAXED, __HIP_MEMORY_SCOPE_SYSTEM);
}
__device__ inline void st4_sys(unsigned* p, unsigned v) {
  __hip_atomic_store(p, v, __ATOMIC_RELAXED, __HIP_MEMORY_SCOPE_SYSTEM);
}
__device__ inline void stf_sys(float* p, float v) {
  __hip_atomic_store(p, v, __ATOMIC_RELAXED, __HIP_MEMORY_SCOPE_SYSTEM);
}
__device__ inline float ldf_sys(const float* p) {
  return __hip_atomic_load(p, __ATOMIC_RELAXED, __HIP_MEMORY_SCOPE_SYSTEM);
}

__global__ void __launch_bounds__(128, 1)
ContextAwareModel_9655086481739_kernel(
    const int* __restrict__ contexts, const int* __restrict__ positions,
    const float* __restrict__ emb,
    const float* __restrict__ wih0, const float* __restrict__ whh0,
    const float* __restrict__ bih0, const float* __restrict__ bhh0,
    const float* __restrict__ wih1, const float* __restrict__ whh1,
    const float* __restrict__ bih1, const float* __restrict__ bhh1,
    const float* __restrict__ wcls, const float* __restrict__ bcls,
    float* __restrict__ out, unsigned char* __restrict__ ws)
{
  __shared__ unsigned short smem[32 * ROWP1];   // 49,664 B

  const int wg   = blockIdx.x;
  const int tid  = threadIdx.x;
  const int layer  = wg >> 7;
  const int d      = (wg >> 6) & 1;
  const int colblk = (wg >> 1) & 31;
  const int mhalf  = wg & 1;
  const int wv   = tid >> 6;
  const int lane = tid & 63;
  const int quad = lane >> 4;
  const int lc   = lane & 15;
  const int hc0  = colblk * 8;
  const int hc   = hc0 + (lc & 7);
  const int m0   = mhalf * 32 + wv * 16;
  const int r_base = m0 + quad * 4;

  unsigned short* Xbuf = (unsigned short*)ws;
  u64*      h0t   = (u64*)(ws + H0T_OFF);
  u64*      h1t   = (u64*)(ws + H1T_OFF);
  unsigned* eflag = (unsigned*)(ws + EFLAG_OFF);
  float*    tgt   = out + 256;                 // target_output lives in out directly

  const int ROWP = layer ? ROWP1 : ROWP0;

  // ---------------- stage 0 ----------------
  { // zero all tag-carrying words + end flags (fresh every launch)
    u64* zp = (u64*)(ws + H0T_OFF);
    for (int i = wg * 128 + tid; i < ZERO_U64; i += NWG * 128)
      st8_sys(zp + i, 0ull);
  }
  { // embedding gather -> bf16, padded to 320
    int gw2 = wg * 2 + wv;                     // 0..511 waves
    for (int rl = 0; rl < 64; ++rl) {
      int rr = gw2 * 64 + rl;                  // rr = t*64 + b
      int t = rr >> 6, b = rr & 63;
      int tok = contexts[b * S_LEN + t];
      const float* erow = emb + (long)tok * EMBD;
#pragma unroll
      for (int i = 0; i < 5; ++i) {
        int kk = i * 64 + lane;
        float v = (kk < EMBD) ? erow[kk] : 0.f;
        if (kk < XPAD) Xbuf[rr * XPAD + kk] = f2bf(v);
      }
    }
  }
  { // weights -> LDS (bf16). Row lr: tile T=lr>>4, col c=lr&15, gate = T*2+(c>>3)
    const float* wih = layer ? wih1 : wih0;
    const float* whh = layer ? whh1 : whh0;
    const int KI  = layer ? 512 : 300;
    const int KIp = layer ? 512 : 320;
    const int KT  = layer ? 768 : 576;
    int lr = tid >> 2, sub = tid & 3;
    int c = lr & 15, T = lr >> 4;
    int gate = T * 2 + (c >> 3);
    int j = gate * 256 + hc0 + (c & 7);
    const float* wri = wih + (long)(d * 1024 + j) * KI;
    const float* wrh = whh + (long)(d * 1024 + j) * 256;
    for (int kk = sub; kk < ROWP; kk += 4) {
      float v = 0.f;
      if (kk < KI) v = wri[kk];
      else if (kk >= KIp && kk < KT) v = wrh[kk - KIp];
      smem[lr * ROWP + kk] = f2bf(v);
    }
  }
  float bias0, bias1;
  {
    const float* bi = layer ? bih1 : bih0;
    const float* bh = layer ? bhh1 : bhh0;
    int j0 = ((lc >> 3) & 1) * 256 + hc;        // gate i/f
    int j1 = (2 + ((lc >> 3) & 1)) * 256 + hc;  // gate g/o
    bias0 = bi[d * 1024 + j0] + bh[d * 1024 + j0];
    bias1 = bi[d * 1024 + j1] + bh[d * 1024 + j1];
  }
  int pos[4];
#pragma unroll
  for (int j = 0; j < 4; ++j) pos[j] = positions[r_base + j];
  float cst[4] = {0.f, 0.f, 0.f, 0.f};
  const unsigned short* lds_t0 = smem + lc * ROWP + quad * 8;
  const unsigned short* lds_t1 = smem + (16 + lc) * ROWP + quad * 8;
  const bool hi = (lc & 8) != 0;

  // one cooperative sync: publishes Xbuf, LDS weights, zeroed tags
  cooperative_groups::grid_group gg = cooperative_groups::this_grid();
  __syncthreads();
  gg.sync();

  // ---------------- recurrence: sentinel-paced wave pipelines ----------------
  if (layer == 0) {
    for (int t = 0; t < S_LEN; ++t) {
      // --- issue sentinel loads FIRST (hide RTT under x-part MFMAs) ---
      // lanes 0..31: data sentinel = producer colblk=lane's LAST store of step
      //   t-1 (row m0+15, word 3) in h0 slot (t-1)&3, own dir.
      // lanes 32..63: back-pressure = L1 output tags (both dirs, colblk=lane-32,
      //   row m0 word 0) >= t-3  ==> L1 finished step t-4, h0 slot t&3 reusable.
      const bool needD = (t > 0) && (lane < 32);
      const bool needB = (t >= 4) && (lane >= 32);
      const u64* sentp = h0t + (((t + 3) & 3) * 16384 + (m0 + 15) * 256 + d * 128 + (lane & 31) * 4 + 3);
      const u64* bp0   = h1t + ((t & 1) * 16384 + m0 * 256 + (lane & 31) * 4);
      const u64* bp1   = bp0 + 128;
      u64 sv  = needD ? ld_sys64(sentp) : 0;
      u64 b0v = needB ? ld_sys64(bp0) : 0;
      u64 b1v = needB ? ld_sys64(bp1) : 0;

      v4f acc0 = {bias0, bias0, bias0, bias0};
      v4f acc1 = {bias1, bias1, bias1, bias1};
      { // x-part GEMM: h-independent, overlaps sentinel flight
        const unsigned short* aP1 = Xbuf + (t * BATCH + m0 + lc) * XPAD + quad * 8;
#pragma unroll
        for (int i = 0; i < 10; ++i) {
          v8s av = *(const v8s*)(aP1 + i * 32);
          v8s b0 = *(const v8s*)(lds_t0 + i * 32);
          v8s b1 = *(const v8s*)(lds_t1 + i * 32);
          acc0 = __builtin_amdgcn_mfma_f32_16x16x32_bf16(av, b0, acc0, 0, 0, 0);
          acc1 = __builtin_amdgcn_mfma_f32_16x16x32_bf16(av, b1, acc1, 0, 0, 0);
        }
      }
      { // sentinel spin: 1-2 small words per lane per round
        const unsigned thrD = (unsigned)t;
        const unsigned thrB = (unsigned)(t - 3);
        for (;;) {
          bool ok = (!needD || ((unsigned)(sv >> 32) == thrD))
                 && (!needB || (((unsigned)(b0v >> 32) >= thrB) &&
                                ((unsigned)(b1v >> 32) >= thrB)));
          if (__all(ok)) break;
          __builtin_amdgcn_s_sleep(1);
          if (needD) sv = ld_sys64(sentp);
          if (needB) { b0v = ld_sys64(bp0); b1v = ld_sys64(bp1); }
        }
      }
      if (t > 0) { // bulk load ONCE, tag-verified (retry = rare straggler fallback)
        const u64* hp = h0t + (((t + 3) & 3) * 16384 + (m0 + lc) * 256 + d * 128 + quad * 4);
        const unsigned T = (unsigned)t;
        u64 w[32];
        for (;;) {
#pragma unroll
          for (int i = 0; i < 8; ++i)
#pragma unroll
            for (int k = 0; k < 4; ++k)
              w[i * 4 + k] = ld_sys64(hp + i * 16 + k);
          unsigned diff = 0;
#pragma unroll
          for (int i = 0; i < 32; ++i) diff |= (unsigned)(w[i] >> 32) ^ T;
          if (__all(diff == 0)) break;
          __builtin_amdgcn_s_sleep(1);
        }
#pragma unroll
        for (int i = 0; i < 8; ++i) {
          union { unsigned u[4]; v8s s; } f;
          f.u[0] = (unsigned)w[i * 4 + 0];
          f.u[1] = (unsigned)w[i * 4 + 1];
          f.u[2] = (unsigned)w[i * 4 + 2];
          f.u[3] = (unsigned)w[i * 4 + 3];
          v8s b0 = *(const v8s*)(lds_t0 + 320 + i * 32);
          v8s b1 = *(const v8s*)(lds_t1 + 320 + i * 32);
          acc0 = __builtin_amdgcn_mfma_f32_16x16x32_bf16(f.s, b0, acc0, 0, 0, 0);
          acc1 = __builtin_amdgcn_mfma_f32_16x16x32_bf16(f.s, b1, acc1, 0, 0, 0);
        }
      }
      const u64 tagbits = ((u64)(unsigned)(t + 1)) << 32;
#pragma unroll
      for (int j = 0; j < 4; ++j) {
        float a0 = acc0[j], a1 = acc1[j];
        float o0 = __shfl_xor(a0, 8);
        float o1 = __shfl_xor(a1, 8);
        float iv = hi ? o0 : a0;
        float fv = hi ? a0 : o0;
        float gv = hi ? o1 : a1;
        float ov = hi ? a1 : o1;
        float ii = sigm(iv), ff = sigm(fv), ggt = tanhf_(gv), oo = sigm(ov);
        float cn = ff * cst[j] + ii * ggt;
        cst[j] = cn;
        float hv = oo * tanhf_(cn);
        unsigned hb = f2bf(hv);
        unsigned ob = ((unsigned)__shfl_xor((int)hb, 1)) & 0xFFFFu;
        if (lc < 8 && !(lc & 1)) {
          unsigned word = hb | (ob << 16);
          st8_sys(h0t + ((t & 3) * 16384 + (r_base + j) * 256 + d * 128 + colblk * 4 + (lc >> 1)),
                  (u64)word | tagbits);
        }
      }
    }
  } else {
    for (int t = 0; t < S_LEN; ++t) {
      // --- sentinels for BOTH phases, one merged spin ---
      // lanes 0..31: phase-A sentinel (h1_{t-1}, own dir, producer colblk=lane)
      // all lanes : phase-B sentinel (h0_t, dir=lane>>5, colblk=lane&31)
      const bool needA = (t > 0) && (lane < 32);
      const u64* sAp = h1t + (((t + 1) & 1) * 16384 + (m0 + 15) * 256 + d * 128 + (lane & 31) * 4 + 3);
      const u64* sBp = h0t + ((t & 3) * 16384 + (m0 + 15) * 256 + (lane >> 5) * 128 + (lane & 31) * 4 + 3);
      u64 av = needA ? ld_sys64(sAp) : 0;
      u64 bv = ld_sys64(sBp);
      const unsigned tA = (unsigned)t, tB = (unsigned)(t + 1);
      for (;;) {
        bool ok = (!needA || ((unsigned)(av >> 32) == tA))
               && ((unsigned)(bv >> 32) == tB);
        if (__all(ok)) break;
        __builtin_amdgcn_s_sleep(1);
        if (needA) av = ld_sys64(sAp);
        bv = ld_sys64(sBp);
      }
      v4f acc0 = {bias0, bias0, bias0, bias0};
      v4f acc1 = {bias1, bias1, bias1, bias1};
      if (t > 0) { // phase A: h1_{t-1}, own dir — bulk once, verified
        const u64* hp = h1t + (((t + 1) & 1) * 16384 + (m0 + lc) * 256 + d * 128 + quad * 4);
        u64 w[32];
        for (;;) {
#pragma unroll
          for (int i = 0; i < 8; ++i)
#pragma unroll
            for (int k = 0; k < 4; ++k)
              w[i * 4 + k] = ld_sys64(hp + i * 16 + k);
          unsigned diff = 0;
#pragma unroll
          for (int i = 0; i < 32; ++i) diff |= (unsigned)(w[i] >> 32) ^ tA;
          if (__all(diff == 0)) break;
          __builtin_amdgcn_s_sleep(1);
        }
#pragma unroll
        for (int i = 0; i < 8; ++i) {
          union { unsigned u[4]; v8s s; } f;
          f.u[0] = (unsigned)w[i * 4 + 0];
          f.u[1] = (unsigned)w[i * 4 + 1];
          f.u[2] = (unsigned)w[i * 4 + 2];
          f.u[3] = (unsigned)w[i * 4 + 3];
          v8s b0 = *(const v8s*)(lds_t0 + 512 + i * 32);
          v8s b1 = *(const v8s*)(lds_t1 + 512 + i * 32);
          acc0 = __builtin_amdgcn_mfma_f32_16x16x32_bf16(f.s, b0, acc0, 0, 0, 0);
          acc1 = __builtin_amdgcn_mfma_f32_16x16x32_bf16(f.s, b1, acc1, 0, 0, 0);
        }
      }
      { // phase B: h0_t, dir 0 then dir 1 — two verified 32-word batches
        const u64* hpB = h0t + ((t & 3) * 16384 + (m0 + lc) * 256 + quad * 4);
#pragma unroll
        for (int half = 0; half < 2; ++half) {
          const u64* hp = hpB + half * 128;
          u64 w[32];
          for (;;) {
#pragma unroll
            for (int i = 0; i < 8; ++i)
#pragma unroll
              for (int k = 0; k < 4; ++k)
                w[i * 4 + k] = ld_sys64(hp + i * 16 + k);
            unsigned diff = 0;
#pragma unroll
            for (int i = 0; i < 32; ++i) diff |= (unsigned)(w[i] >> 32) ^ tB;
            if (__all(diff == 0)) break;
            __builtin_amdgcn_s_sleep(1);
          }
#pragma unroll
          for (int i = 0; i < 8; ++i) {
            union { unsigned u[4]; v8s s; } f;
            f.u[0] = (unsigned)w[i * 4 + 0];
            f.u[1] = (unsigned)w[i * 4 + 1];
            f.u[2] = (unsigned)w[i * 4 + 2];
            f.u[3] = (unsigned)w[i * 4 + 3];
            v8s b0 = *(const v8s*)(lds_t0 + (half * 8 + i) * 32);
            v8s b1 = *(const v8s*)(lds_t1 + (half * 8 + i) * 32);
            acc0 = __builtin_amdgcn_mfma_f32_16x16x32_bf16(f.s, b0, acc0, 0, 0, 0);
            acc1 = __builtin_amdgcn_mfma_f32_16x16x32_bf16(f.s, b1, acc1, 0, 0, 0);
          }
        }
      }
      const u64 tagbits = ((u64)(unsigned)(t + 1)) << 32;
#pragma unroll
      for (int j = 0; j < 4; ++j) {
        float a0 = acc0[j], a1 = acc1[j];
        float o0 = __shfl_xor(a0, 8);
        float o1 = __shfl_xor(a1, 8);
        float iv = hi ? o0 : a0;
        float fv = hi ? a0 : o0;
        float gv = hi ? o1 : a1;
        float ov = hi ? a1 : o1;
        float ii = sigm(iv), ff = sigm(fv), ggt = tanhf_(gv), oo = sigm(ov);
        float cn = ff * cst[j] + ii * ggt;
        cst[j] = cn;
        float hv = oo * tanhf_(cn);
        unsigned hb = f2bf(hv);
        unsigned ob = ((unsigned)__shfl_xor((int)hb, 1)) & 0xFFFFu;
        int r = r_base + j;
        if (lc < 8 && !(lc & 1)) {
          unsigned word = hb | (ob << 16);
          st8_sys(h1t + ((t & 1) * 16384 + r * 256 + d * 128 + colblk * 4 + (lc >> 1)),
                  (u64)word | tagbits);
        }
        if (lc < 8 && pos[j] == t) stf_sys(&tgt[r * 512 + d * 256 + hc], hv);
      }
    }
    // publish completion: tgt stores drained, then end flag (release pattern)
    asm volatile("s_waitcnt vmcnt(0)" ::: "memory");
    st4_sys(eflag + (wg - 128) * 2 + wv, 1u);
  }

  // ---------------- epilogue (layer-0 wg<64 waves only) ----------------
  {
    int gw = wg * 2 + wv;
    if (gw < 128) {                 // one wave per (b, class)
      for (;;) {                    // join: all 256 layer-1 waves finished
        bool ok = true;
#pragma unroll
        for (int k = 0; k < 4; ++k) ok &= (ldu_sys(eflag + k * 64 + lane) != 0u);
        if (__all(ok)) break;
        __builtin_amdgcn_s_sleep(4);
      }
      int b = gw >> 1, cl2 = gw & 1;
      float s = 0.f;
#pragma unroll
      for (int i = 0; i < 8; ++i) {
        int jj = i * 64 + lane;
        s += ldf_sys(&tgt[b * 512 + jj]) * wcls[cl2 * 512 + jj];
      }
      s += __shfl_xor(s, 32); s += __shfl_xor(s, 16); s += __shfl_xor(s, 8);
      s += __shfl_xor(s, 4);  s += __shfl_xor(s, 2);  s += __shfl_xor(s, 1);
      if (lane == 0) {
        float L = s + bcls[cl2];
        out[b * 2 + cl2] = L;             // logits
        out[128 + b * 2 + cl2] = sigm(L); // probs
      }
    }
  }
}

extern "C" void kernel_launch(void* const* d_in, const int* in_sizes, int n_in,
                              void* d_out, int out_size, void* d_ws, size_t ws_size,
                              hipStream_t stream) {
  (void)in_sizes; (void)n_in; (void)out_size; (void)ws_size;
  const int*   contexts  = (const int*)d_in[0];
  const int*   positions = (const int*)d_in[1];
  const float* emb   = (const float*)d_in[2];
  const float* wih0  = (const float*)d_in[3];
  const float* whh0  = (const float*)d_in[4];
  const float* bih0  = (const float*)d_in[5];
  const float* bhh0  = (const float*)d_in[6];
  const float* wih1  = (const float*)d_in[7];
  const float* whh1  = (const float*)d_in[8];
  const float* bih1  = (const float*)d_in[9];
  const float* bhh1  = (const float*)d_in[10];
  const float* wcls  = (const float*)d_in[11];
  const float* bcls  = (const float*)d_in[12];
  float* out = (float*)d_out;
  unsigned char* ws = (unsigned char*)d_ws;

  void* args[] = { &contexts, &positions, &emb,
                   &wih0, &whh0, &bih0, &bhh0,
                   &wih1, &whh1, &bih1, &bhh1,
                   &wcls, &bcls, &out, &ws };
  hipLaunchCooperativeKernel((const void*)ContextAwareModel_9655086481739_kernel,
                             dim3(NWG), dim3(128), args, 0, stream);
}

// Round 3
// 3406.679 us; speedup vs baseline: 1.4596x; 1.3206x over previous
//
#include <hip/hip_runtime.h>
#include <hip/hip_cooperative_groups.h>

// Persistent cooperative LSTM kernel.
// R1..R5: grid.sync -> hand barrier -> coherent IC path -> decoupled group chains
//   w/ flag words + wave-parallel polling: 5.7us/step (2930us).
// R6 (9.5us/step): tags on every data u64; poll re-loaded full operand block
//   every round -> retry/fetch storm.
// R7 (8.6us/step): sentinel=last data word + verified bulk. FAILED: one lane's
//   last store does NOT imply other lanes' stores visible -> verify retries fire
//   constantly (FETCH still +147MB vs R5).
// R8: R5's PROVEN ordering (stores -> vmcnt(0) drain -> publish) made per-WAVE:
//   - dedicated sentinel u32 per producer wave (monotonic step tag), stored
//     after the drain => sentinel visible implies tile visible (no verify, no
//     retry, data loaded ONCE)
//   - data back to packed bf16 (R5 layout, half the h traffic of R6/R7)
//   - NO per-step __syncthreads (2 waves of a WG fully decoupled)
//   - wave-parallel sentinel spin (1-2 u32/lane covers all producers +
//     back-pressure in one RTT/round), issued before x-GEMM on L0 to hide RTT
//   - h-data needs no zero-init (never read before tag>=1); only 7KB sentinels

typedef short v8s __attribute__((ext_vector_type(8)));
typedef float v4f __attribute__((ext_vector_type(4)));
typedef unsigned long long u64;

#define S_LEN 512
#define BATCH 64
#define EMBD  300
#define XPAD  320
#define ROWP0 584   // 320 (x, padded) + 256 (h) + 8 pad
#define ROWP1 776   // 512 (x1) + 256 (h) + 8 pad
#define NWG   256

// workspace layout (bytes):
//   Xbuf [512][64][320] bf16            @ 0          (20,971,520)
//   h0buf bf16 [4][64][512] (ring 4)    @ 20,971,520 (262,144)
//   h1buf bf16 [2][2][64][256] (ring 2) @ 21,233,664 (131,072)
//   sent0 u32 [4][2][2][2][32]          @ 21,364,736 (4,096)
//   sent1 u32 [2][2][2][2][32]          @ 21,368,832 (2,048)
//   eflag u32 [256]                     @ 21,370,880 (1,024)  top: 21,371,904
#define H0_OFF    20971520u
#define H1_OFF    (H0_OFF + 262144u)
#define SENT0_OFF (H1_OFF + 131072u)
#define SENT1_OFF (SENT0_OFF + 4096u)
#define EFLAG_OFF (SENT1_OFF + 2048u)
#define ZERO_U32  1792   // (4096 + 2048 + 1024) / 4

__device__ inline unsigned short f2bf(float x) {
  union { float f; unsigned u; } v; v.f = x;
  unsigned r = v.u + 0x7FFF + ((v.u >> 16) & 1);   // RNE
  return (unsigned short)(r >> 16);
}
__device__ inline float sigm(float x) { return 1.f / (1.f + __expf(-x)); }
__device__ inline float tanhf_(float x) {
  float e = __expf(-2.f * fabsf(x));
  float r = (1.f - e) / (1.f + e);
  return x >= 0.f ? r : -r;
}

// IC-coherent accessors — SYSTEM scope, proven data path (R2..R5).
__device__ inline v8s ld_sys16(const unsigned short* p) {
  union { u64 q[2]; v8s s; } u;
  u.q[0] = __hip_atomic_load((const u64*)p,     __ATOMIC_RELAXED, __HIP_MEMORY_SCOPE_SYSTEM);
  u.q[1] = __hip_atomic_load((const u64*)p + 1, __ATOMIC_RELAXED, __HIP_MEMORY_SCOPE_SYSTEM);
  return u.s;
}
__device__ inline unsigned ldu_sys(const unsigned* p) {
  return __hip_atomic_load(p, __ATOMIC_RELAXED, __HIP_MEMORY_SCOPE_SYSTEM);
}
__device__ inline void st4_sys(unsigned* p, unsigned v) {
  __hip_atomic_store(p, v, __ATOMIC_RELAXED, __HIP_MEMORY_SCOPE_SYSTEM);
}
__device__ inline void stf_sys(float* p, float v) {
  __hip_atomic_store(p, v, __ATOMIC_RELAXED, __HIP_MEMORY_SCOPE_SYSTEM);
}
__device__ inline float ldf_sys(const float* p) {
  return __hip_atomic_load(p, __ATOMIC_RELAXED, __HIP_MEMORY_SCOPE_SYSTEM);
}

template<int NKA, int NKB, int P2OFF>
__device__ inline void mfma_dual(const v8s* a, const unsigned short* t0,
                                 const unsigned short* t1, v4f& acc0, v4f& acc1) {
#pragma unroll
  for (int i = 0; i < NKA; ++i) {
    v8s b0 = *(const v8s*)(t0 + i * 32);
    v8s b1 = *(const v8s*)(t1 + i * 32);
    acc0 = __builtin_amdgcn_mfma_f32_16x16x32_bf16(a[i], b0, acc0, 0, 0, 0);
    acc1 = __builtin_amdgcn_mfma_f32_16x16x32_bf16(a[i], b1, acc1, 0, 0, 0);
  }
#pragma unroll
  for (int i = 0; i < NKB; ++i) {
    v8s b0 = *(const v8s*)(t0 + P2OFF + i * 32);
    v8s b1 = *(const v8s*)(t1 + P2OFF + i * 32);
    acc0 = __builtin_amdgcn_mfma_f32_16x16x32_bf16(a[NKA + i], b0, acc0, 0, 0, 0);
    acc1 = __builtin_amdgcn_mfma_f32_16x16x32_bf16(a[NKA + i], b1, acc1, 0, 0, 0);
  }
}

__global__ void __launch_bounds__(128, 1)
ContextAwareModel_9655086481739_kernel(
    const int* __restrict__ contexts, const int* __restrict__ positions,
    const float* __restrict__ emb,
    const float* __restrict__ wih0, const float* __restrict__ whh0,
    const float* __restrict__ bih0, const float* __restrict__ bhh0,
    const float* __restrict__ wih1, const float* __restrict__ whh1,
    const float* __restrict__ bih1, const float* __restrict__ bhh1,
    const float* __restrict__ wcls, const float* __restrict__ bcls,
    float* __restrict__ out, unsigned char* __restrict__ ws)
{
  __shared__ unsigned short smem[32 * ROWP1];   // 49,664 B

  const int wg   = blockIdx.x;
  const int tid  = threadIdx.x;
  const int layer  = wg >> 7;
  const int d      = (wg >> 6) & 1;
  const int colblk = (wg >> 1) & 31;
  const int mhalf  = wg & 1;
  const int wv   = tid >> 6;
  const int lane = tid & 63;
  const int quad = lane >> 4;
  const int lc   = lane & 15;
  const int hc0  = colblk * 8;
  const int hc   = hc0 + (lc & 7);
  const int m0   = mhalf * 32 + wv * 16;
  const int r_base = m0 + quad * 4;

  unsigned short* Xbuf  = (unsigned short*)ws;
  unsigned short* h0buf = (unsigned short*)(ws + H0_OFF);
  unsigned short* h1buf = (unsigned short*)(ws + H1_OFF);
  unsigned*       sent0 = (unsigned*)(ws + SENT0_OFF);
  unsigned*       sent1 = (unsigned*)(ws + SENT1_OFF);
  unsigned*       eflag = (unsigned*)(ws + EFLAG_OFF);
  float*          tgt   = out + 256;           // target_output lives in out directly

  const int ROWP = layer ? ROWP1 : ROWP0;
  // sentinel slot index helpers: [slot][dir][mhalf][wv][colblk]
  const int sgrp = ((mhalf << 1) | wv) << 5;   // (mhalf, wv) base, colblk fastest

  // ---------------- stage 0 ----------------
  { // zero sentinels + end flags (fresh every launch); h-data needs no zeroing
    unsigned* zp = (unsigned*)(ws + SENT0_OFF);
    for (int i = wg * 128 + tid; i < ZERO_U32; i += NWG * 128) st4_sys(zp + i, 0u);
  }
  { // embedding gather -> bf16, padded to 320
    int gw2 = wg * 2 + wv;                     // 0..511 waves
    for (int rl = 0; rl < 64; ++rl) {
      int rr = gw2 * 64 + rl;                  // rr = t*64 + b
      int t = rr >> 6, b = rr & 63;
      int tok = contexts[b * S_LEN + t];
      const float* erow = emb + (long)tok * EMBD;
#pragma unroll
      for (int i = 0; i < 5; ++i) {
        int kk = i * 64 + lane;
        float v = (kk < EMBD) ? erow[kk] : 0.f;
        if (kk < XPAD) Xbuf[rr * XPAD + kk] = f2bf(v);
      }
    }
  }
  { // weights -> LDS (bf16). Row lr: tile T=lr>>4, col c=lr&15, gate = T*2+(c>>3)
    const float* wih = layer ? wih1 : wih0;
    const float* whh = layer ? whh1 : whh0;
    const int KI  = layer ? 512 : 300;
    const int KIp = layer ? 512 : 320;
    const int KT  = layer ? 768 : 576;
    int lr = tid >> 2, sub = tid & 3;
    int c = lr & 15, T = lr >> 4;
    int gate = T * 2 + (c >> 3);
    int j = gate * 256 + hc0 + (c & 7);
    const float* wri = wih + (long)(d * 1024 + j) * KI;
    const float* wrh = whh + (long)(d * 1024 + j) * 256;
    for (int kk = sub; kk < ROWP; kk += 4) {
      float v = 0.f;
      if (kk < KI) v = wri[kk];
      else if (kk >= KIp && kk < KT) v = wrh[kk - KIp];
      smem[lr * ROWP + kk] = f2bf(v);
    }
  }
  float bias0, bias1;
  {
    const float* bi = layer ? bih1 : bih0;
    const float* bh = layer ? bhh1 : bhh0;
    int j0 = ((lc >> 3) & 1) * 256 + hc;        // gate i/f
    int j1 = (2 + ((lc >> 3) & 1)) * 256 + hc;  // gate g/o
    bias0 = bi[d * 1024 + j0] + bh[d * 1024 + j0];
    bias1 = bi[d * 1024 + j1] + bh[d * 1024 + j1];
  }
  int pos[4];
#pragma unroll
  for (int j = 0; j < 4; ++j) pos[j] = positions[r_base + j];
  float cst[4] = {0.f, 0.f, 0.f, 0.f};
  const unsigned short* lds_t0 = smem + lc * ROWP + quad * 8;
  const unsigned short* lds_t1 = smem + (16 + lc) * ROWP + quad * 8;
  const bool hi = (lc & 8) != 0;
  unsigned* myflag = (layer == 0)
      ? sent0 + 0 /* rebased per-step below */ : sent1;

  // one cooperative sync: publishes Xbuf, LDS weights, zeroed sentinels
  cooperative_groups::grid_group gg = cooperative_groups::this_grid();
  __syncthreads();
  gg.sync();

  // ---------------- recurrence: drain->sentinel paced wave pipelines ----------
  if (layer == 0) {
    for (int t = 0; t < S_LEN; ++t) {
      // sentinel loads first (RTT hides under x-GEMM):
      //  lanes 0..31 : own-dir h0 producers, slot (t-1)&3, tag >= t
      //  lanes 32..63: back-pressure, L1 both dirs slot t&1, tag >= t-3
      const bool needD = (t > 0) && (lane < 32);
      const bool needB = (t >= 4) && (lane >= 32);
      const unsigned* sDp = sent0 + ((((t + 3) & 3) * 2 + d) * 4 * 32 + sgrp + (lane & 31));
      const unsigned* sB0 = sent1 + (((t & 1) * 2 + 0) * 4 * 32 + sgrp + (lane & 31));
      const unsigned* sB1 = sent1 + (((t & 1) * 2 + 1) * 4 * 32 + sgrp + (lane & 31));
      unsigned vD = needD ? ldu_sys(sDp) : 0u;
      unsigned v0 = needB ? ldu_sys(sB0) : 0u;
      unsigned v1 = needB ? ldu_sys(sB1) : 0u;

      v4f acc0 = {bias0, bias0, bias0, bias0};
      v4f acc1 = {bias1, bias1, bias1, bias1};
      { // x-part GEMM: h-independent, overlaps sentinel flight
        const unsigned short* aP1 = Xbuf + (t * BATCH + m0 + lc) * XPAD + quad * 8;
#pragma unroll
        for (int i = 0; i < 10; ++i) {
          v8s av = *(const v8s*)(aP1 + i * 32);
          v8s b0 = *(const v8s*)(lds_t0 + i * 32);
          v8s b1 = *(const v8s*)(lds_t1 + i * 32);
          acc0 = __builtin_amdgcn_mfma_f32_16x16x32_bf16(av, b0, acc0, 0, 0, 0);
          acc1 = __builtin_amdgcn_mfma_f32_16x16x32_bf16(av, b1, acc1, 0, 0, 0);
        }
      }
      { // wave-parallel sentinel spin: 1-2 u32 per lane per round
        const unsigned thrD = (unsigned)t, thrB = (unsigned)(t - 3);
        for (;;) {
          bool ok = (!needD || (vD >= thrD))
                 && (!needB || ((v0 >= thrB) && (v1 >= thrB)));
          if (__all(ok)) break;
          __builtin_amdgcn_s_sleep(1);
          if (needD) vD = ldu_sys(sDp);
          if (needB) { v0 = ldu_sys(sB0); v1 = ldu_sys(sB1); }
        }
        asm volatile("" ::: "memory");   // no data-load hoist above the spin
      }
      if (t > 0) { // h0_{t-1}, own dir — load ONCE, valid by protocol
        const unsigned short* aP2 = h0buf + ((t + 3) & 3) * 32768 + (m0 + lc) * 512 + d * 256 + quad * 8;
        v8s a[8];
#pragma unroll
        for (int i = 0; i < 8; ++i) a[i] = ld_sys16(aP2 + i * 32);
#pragma unroll
        for (int i = 0; i < 8; ++i) {
          v8s b0 = *(const v8s*)(lds_t0 + 320 + i * 32);
          v8s b1 = *(const v8s*)(lds_t1 + 320 + i * 32);
          acc0 = __builtin_amdgcn_mfma_f32_16x16x32_bf16(a[i], b0, acc0, 0, 0, 0);
          acc1 = __builtin_amdgcn_mfma_f32_16x16x32_bf16(a[i], b1, acc1, 0, 0, 0);
        }
      }
#pragma unroll
      for (int j = 0; j < 4; ++j) {
        float a0 = acc0[j], a1 = acc1[j];
        float o0 = __shfl_xor(a0, 8);
        float o1 = __shfl_xor(a1, 8);
        float iv = hi ? o0 : a0;
        float fv = hi ? a0 : o0;
        float gv = hi ? o1 : a1;
        float ov = hi ? a1 : o1;
        float ii = sigm(iv), ff = sigm(fv), ggt = tanhf_(gv), oo = sigm(ov);
        float cn = ff * cst[j] + ii * ggt;
        cst[j] = cn;
        float hv = oo * tanhf_(cn);
        unsigned hb = f2bf(hv);
        unsigned ob = ((unsigned)__shfl_xor((int)hb, 1)) & 0xFFFFu;
        if (lc < 8 && !(lc & 1)) {
          unsigned word = hb | (ob << 16);
          st4_sys((unsigned*)&h0buf[(t & 3) * 32768 + (r_base + j) * 512 + d * 256 + hc], word);
        }
      }
      // publish: drain store acks, THEN sentinel (visibility-ordered, per-wave)
      asm volatile("s_waitcnt vmcnt(0)" ::: "memory");
      if (lane == 0)
        st4_sys(sent0 + (((t & 3) * 2 + d) * 4 * 32 + sgrp + colblk), (unsigned)(t + 1));
    }
  } else {
    for (int t = 0; t < S_LEN; ++t) {
      // merged sentinel spin for both phases:
      //  lanes 0..31 : phase A (h1_{t-1}, own dir, slot (t-1)&1, tag >= t)
      //                + phase B dir0 (h0_t slot t&3, tag >= t+1)
      //  lanes 32..63: phase B dir1
      const bool needA = (t > 0) && (lane < 32);
      const unsigned* sAp = sent1 + ((((t + 1) & 1) * 2 + d) * 4 * 32 + sgrp + (lane & 31));
      const unsigned* sBp = sent0 + (((t & 3) * 2 + (lane >> 5)) * 4 * 32 + sgrp + (lane & 31));
      unsigned vA = needA ? ldu_sys(sAp) : 0u;
      unsigned vB = ldu_sys(sBp);
      {
        const unsigned thrA = (unsigned)t, thrB = (unsigned)(t + 1);
        for (;;) {
          bool ok = (!needA || (vA >= thrA)) && (vB >= thrB);
          if (__all(ok)) break;
          __builtin_amdgcn_s_sleep(1);
          if (needA) vA = ldu_sys(sAp);
          vB = ldu_sys(sBp);
        }
        asm volatile("" ::: "memory");
      }
      v8s a[24];
      { // h0_t (both dirs) + h1_{t-1} (own dir) — load ONCE, valid by protocol
        const unsigned short* p = h0buf + (t & 3) * 32768 + (m0 + lc) * 512 + quad * 8;
#pragma unroll
        for (int i = 0; i < 16; ++i) a[i] = ld_sys16(p + i * 32);
        const unsigned short* q = h1buf + ((t + 1) & 1) * 32768 + d * 16384 + (m0 + lc) * 256 + quad * 8;
#pragma unroll
        for (int i = 0; i < 8; ++i) a[16 + i] = ld_sys16(q + i * 32);
      }
      v4f acc0 = {bias0, bias0, bias0, bias0};
      v4f acc1 = {bias1, bias1, bias1, bias1};
      mfma_dual<16, 8, 512>(a, lds_t0, lds_t1, acc0, acc1);
#pragma unroll
      for (int j = 0; j < 4; ++j) {
        float a0 = acc0[j], a1 = acc1[j];
        float o0 = __shfl_xor(a0, 8);
        float o1 = __shfl_xor(a1, 8);
        float iv = hi ? o0 : a0;
        float fv = hi ? a0 : o0;
        float gv = hi ? o1 : a1;
        float ov = hi ? a1 : o1;
        float ii = sigm(iv), ff = sigm(fv), ggt = tanhf_(gv), oo = sigm(ov);
        float cn = ff * cst[j] + ii * ggt;
        cst[j] = cn;
        float hv = oo * tanhf_(cn);
        unsigned hb = f2bf(hv);
        unsigned ob = ((unsigned)__shfl_xor((int)hb, 1)) & 0xFFFFu;
        int r = r_base + j;
        if (lc < 8 && !(lc & 1)) {
          unsigned word = hb | (ob << 16);
          st4_sys((unsigned*)&h1buf[(t & 1) * 32768 + d * 16384 + r * 256 + hc], word);
        }
        if (lc < 8 && pos[j] == t) stf_sys(&tgt[r * 512 + d * 256 + hc], hv);
      }
      // publish: drain store acks (incl. tgt), THEN sentinel
      asm volatile("s_waitcnt vmcnt(0)" ::: "memory");
      if (lane == 0)
        st4_sys(sent1 + (((t & 1) * 2 + d) * 4 * 32 + sgrp + colblk), (unsigned)(t + 1));
    }
    // completion flag: tgt stores already drained at last-iteration vmcnt(0)
    st4_sys(eflag + (wg - 128) * 2 + wv, 1u);
  }

  // ---------------- epilogue (layer-0 wg<64 waves only) ----------------
  {
    int gw = wg * 2 + wv;
    if (gw < 128) {                 // one wave per (b, class)
      for (;;) {                    // join: all 256 layer-1 waves finished
        bool ok = true;
#pragma unroll
        for (int k = 0; k < 4; ++k) ok &= (ldu_sys(eflag + k * 64 + lane) != 0u);
        if (__all(ok)) break;
        __builtin_amdgcn_s_sleep(4);
      }
      asm volatile("" ::: "memory");
      int b = gw >> 1, cl2 = gw & 1;
      float s = 0.f;
#pragma unroll
      for (int i = 0; i < 8; ++i) {
        int jj = i * 64 + lane;
        s += ldf_sys(&tgt[b * 512 + jj]) * wcls[cl2 * 512 + jj];
      }
      s += __shfl_xor(s, 32); s += __shfl_xor(s, 16); s += __shfl_xor(s, 8);
      s += __shfl_xor(s, 4);  s += __shfl_xor(s, 2);  s += __shfl_xor(s, 1);
      if (lane == 0) {
        float L = s + bcls[cl2];
        out[b * 2 + cl2] = L;             // logits
        out[128 + b * 2 + cl2] = sigm(L); // probs
      }
    }
  }
  (void)myflag;
}

extern "C" void kernel_launch(void* const* d_in, const int* in_sizes, int n_in,
                              void* d_out, int out_size, void* d_ws, size_t ws_size,
                              hipStream_t stream) {
  (void)in_sizes; (void)n_in; (void)out_size; (void)ws_size;
  const int*   contexts  = (const int*)d_in[0];
  const int*   positions = (const int*)d_in[1];
  const float* emb   = (const float*)d_in[2];
  const float* wih0  = (const float*)d_in[3];
  const float* whh0  = (const float*)d_in[4];
  const float* bih0  = (const float*)d_in[5];
  const float* bhh0  = (const float*)d_in[6];
  const float* wih1  = (const float*)d_in[7];
  const float* whh1  = (const float*)d_in[8];
  const float* bih1  = (const float*)d_in[9];
  const float* bhh1  = (const float*)d_in[10];
  const float* wcls  = (const float*)d_in[11];
  const float* bcls  = (const float*)d_in[12];
  float* out = (float*)d_out;
  unsigned char* ws = (unsigned char*)d_ws;

  void* args[] = { &contexts, &positions, &emb,
                   &wih0, &whh0, &bih0, &bhh0,
                   &wih1, &whh1, &bih1, &bhh1,
                   &wcls, &bcls, &out, &ws };
  hipLaunchCooperativeKernel((const void*)ContextAwareModel_9655086481739_kernel,
                             dim3(NWG), dim3(128), args, 0, stream);
}